// Round 1
// baseline (6091.830 us; speedup 1.0000x reference)
//
// BiLSTM tagger — MI355X. Round 0: correctness-first full pipeline.
// Pipeline: detect dtype -> convert weights/biases to ws (bf16/f32) ->
//   char biLSTM (block-parallel, MFMA) -> cat=[word_emb|hf|hb] ->
//   embeds = cat@w_final^T (+perm to [S,B]) -> pre1 = embeds@wih^T+b ->
//   persistent scan layer1 (16 blk/dir, flag barrier) -> pre2 -> scan layer2 ->
//   tag GEMM (+perm to [B,S]).
#include <hip/hip_runtime.h>

typedef unsigned short u16;
typedef short short8 __attribute__((ext_vector_type(8)));
typedef float float4_ __attribute__((ext_vector_type(4)));
typedef short8 short8a __attribute__((may_alias));

#define MFMA16(a, b, c) __builtin_amdgcn_mfma_f32_16x16x32_bf16((a), (b), (c), 0, 0, 0)

static __device__ __forceinline__ float b2f(u16 v) { return __uint_as_float(((unsigned)v) << 16); }
static __device__ __forceinline__ u16 f2b(float f) {
  unsigned x = __float_as_uint(f);
  return (u16)((x + 0x7fffu + ((x >> 16) & 1u)) >> 16);
}
static __device__ __forceinline__ float ldv(const void* p, long long i, int isbf) {
  return isbf ? b2f(((const u16*)p)[i]) : ((const float*)p)[i];
}
static __device__ __forceinline__ float sigm(float x) { return 1.f / (1.f + __expf(-x)); }
static __device__ __forceinline__ float tanh_(float x) { return 1.f - 2.f / (__expf(2.f * x) + 1.f); }
static __device__ __forceinline__ float4_ splat4(float v) { float4_ r; r[0]=v; r[1]=v; r[2]=v; r[3]=v; return r; }

// ---------------- dtype detection (f32 vs bf16 input buffers) ----------------
// bf16 buffers: low 16 bits of each u32 word are another bf16 of a N(0,.05)
// value -> ((w>>8)&0x7f) clusters in [0x36,0x3f]. f32: those are mantissa bits
// (uniform) -> ~8% hit rate.
__global__ __launch_bounds__(256) void k_detect(const unsigned* __restrict__ wtag, int* __restrict__ flag) {
  __shared__ int cs;
  if (threadIdx.x == 0) cs = 0;
  __syncthreads();
  int hits = 0;
  for (int i = threadIdx.x; i < 1024; i += 256) {
    unsigned b = (wtag[i] >> 8) & 0x7fu;
    hits += (b >= 0x36u && b <= 0x3fu) ? 1 : 0;
  }
  atomicAdd(&cs, hits);
  __syncthreads();
  if (threadIdx.x == 0) *flag = (cs > 512) ? 1 : 0;
}

// ---------------- weight conversion to bf16 workspace ----------------
struct WSegs { const void* src[15]; int dst[15]; int n[15]; };
__global__ __launch_bounds__(256) void k_convw(WSegs s, u16* __restrict__ wt, const int* __restrict__ flagp) {
  const int isbf = *flagp;
  const long long total = 9830400;
  for (long long i = (long long)blockIdx.x * 256 + threadIdx.x; i < total; i += (long long)gridDim.x * 256) {
    int k = 0;
#pragma unroll
    for (int j = 1; j < 15; ++j) if (i >= (long long)s.dst[j]) k = j;
    const long long loc = i - s.dst[k];
    float v = 0.f;
    if (s.src[k]) v = ldv(s.src[k], loc, isbf);
    wt[i] = f2b(v);
  }
}

struct BSegs { const void* a[8]; const void* b[8]; int dst[8]; int n[8]; int np[8]; };
__global__ __launch_bounds__(256) void k_convb(BSegs s, float* __restrict__ bias, const int* __restrict__ flagp) {
  const int isbf = *flagp;
  for (int i = blockIdx.x * 256 + threadIdx.x; i < 9536; i += gridDim.x * 256) {
    int k = 0;
#pragma unroll
    for (int j = 1; j < 8; ++j) if (i >= s.dst[j]) k = j;
    const int loc = i - s.dst[k];
    float v = 0.f;
    if (loc < s.n[k]) {
      v = ldv(s.a[k], loc, isbf);
      if (s.b[k]) v += ldv(s.b[k], loc, isbf);
    }
    bias[i] = v;
  }
}

// ---------------- word embedding gather into cat[:,0:256] ----------------
__global__ __launch_bounds__(128) void k_wordgather(const int* __restrict__ sent, const void* __restrict__ wemb,
                                                    u16* __restrict__ cat, const int* __restrict__ flagp) {
  const int n = blockIdx.x;
  const int idx = sent[n];
  const int isbf = *flagp;
  for (int d = threadIdx.x; d < 256; d += 128)
    cat[(long long)n * 512 + d] = f2b(ldv(wemb, (long long)idx * 256 + d, isbf));
}

// ---------------- char biLSTM: 64 seqs/block, 16 steps, D=64 H=128 ----------------
// grid (256, 2=dir). Wave w owns unit-tiles {w, w+4} (32 units) for all 64 seqs.
__global__ __launch_bounds__(256) void k_char(const int* __restrict__ cs, const void* __restrict__ wchar,
                                              const u16* __restrict__ wihF, const u16* __restrict__ whhF,
                                              const u16* __restrict__ wihB, const u16* __restrict__ whhB,
                                              const float* __restrict__ biasF, const float* __restrict__ biasB,
                                              u16* __restrict__ cat, const int* __restrict__ flagp) {
  const int dir = blockIdx.y;
  const int nb = blockIdx.x;
  const u16* wih = dir ? wihB : wihF;
  const u16* whh = dir ? whhB : whhF;
  const float* bias = dir ? biasB : biasF;
  const int isbf = *flagp;
  __shared__ __align__(16) u16 xs[64][72];    // padded rows (144B) -> 2-way banks
  __shared__ __align__(16) u16 hs[64][136];   // padded rows (272B)
  const int tid = threadIdx.x, wv = tid >> 6, lane = tid & 63;
  for (int i = tid; i < 64 * 136; i += 256) ((u16*)hs)[i] = 0;
  float c[2][4][4];
#pragma unroll
  for (int a1 = 0; a1 < 2; ++a1)
#pragma unroll
    for (int a2 = 0; a2 < 4; ++a2)
#pragma unroll
      for (int a3 = 0; a3 < 4; ++a3) c[a1][a2][a3] = 0.f;

  for (int tt = 0; tt < 16; ++tt) {
    const int t = dir ? (15 - tt) : tt;
    {  // gather x_t (padding_idx==0 -> zeros)
      const int sid = tid >> 2, part = tid & 3;
      const int n = nb * 64 + sid;
      const int idx = cs[n * 16 + t];
#pragma unroll
      for (int q = 0; q < 16; ++q) {
        const int d2 = part * 16 + q;
        float v = 0.f;
        if (idx != 0) v = ldv(wchar, (long long)idx * 64 + d2, isbf);
        xs[sid][d2] = f2b(v);
      }
    }
    __syncthreads();  // x_t and h_{t-1} ready
    float4_ acc[2][4][4];
#pragma unroll
    for (int ut = 0; ut < 2; ++ut)
#pragma unroll
      for (int g = 0; g < 4; ++g) {
        const float bv = bias[g * 128 + (wv + 4 * ut) * 16 + (lane & 15)];
#pragma unroll
        for (int rt = 0; rt < 4; ++rt) acc[ut][g][rt] = splat4(bv);
      }
#pragma unroll
    for (int kc = 0; kc < 6; ++kc) {
      short8 a[4];
      if (kc < 2) {
#pragma unroll
        for (int rt = 0; rt < 4; ++rt)
          a[rt] = *(const short8a*)&xs[rt * 16 + (lane & 15)][kc * 32 + (lane >> 4) * 8];
      } else {
#pragma unroll
        for (int rt = 0; rt < 4; ++rt)
          a[rt] = *(const short8a*)&hs[rt * 16 + (lane & 15)][(kc - 2) * 32 + (lane >> 4) * 8];
      }
#pragma unroll
      for (int ut = 0; ut < 2; ++ut)
#pragma unroll
        for (int g = 0; g < 4; ++g) {
          const int col = g * 128 + (wv + 4 * ut) * 16 + (lane & 15);
          short8 bfr;
          if (kc < 2) bfr = *(const short8a*)(wih + col * 64 + kc * 32 + (lane >> 4) * 8);
          else        bfr = *(const short8a*)(whh + col * 128 + (kc - 2) * 32 + (lane >> 4) * 8);
#pragma unroll
          for (int rt = 0; rt < 4; ++rt) acc[ut][g][rt] = MFMA16(a[rt], bfr, acc[ut][g][rt]);
        }
    }
    __syncthreads();  // all reads of hs done before overwrite
#pragma unroll
    for (int ut = 0; ut < 2; ++ut)
#pragma unroll
      for (int rt = 0; rt < 4; ++rt)
#pragma unroll
        for (int r = 0; r < 4; ++r) {
          const float iv = acc[ut][0][rt][r];
          const float fv = acc[ut][1][rt][r];
          const float gv = acc[ut][2][rt][r];
          const float ov = acc[ut][3][rt][r];
          float& cc = c[ut][rt][r];
          cc = sigm(fv) * cc + sigm(iv) * tanh_(gv);
          const float h = sigm(ov) * tanh_(cc);
          const int seq = rt * 16 + (lane >> 4) * 4 + r;
          const int u = (wv + 4 * ut) * 16 + (lane & 15);
          const u16 hv = f2b(h);
          hs[seq][u] = hv;
          if (tt == 15) cat[(long long)(nb * 64 + seq) * 512 + 256 + dir * 128 + u] = hv;
        }
  }
}

// ---------------- generic MFMA GEMM: C[r,j] = A[r,:]*W[j,:] + bias[j] ----------------
// PERM: 0 none; 1 n=b*256+s -> s*64+b (embeds); 2 r=s*64+b -> b*256+s (tag)
// OUTM: 0 bf16; 1 flag-dtype (final output)
template <int TM, int TN, int PERM, int OUTM>
__global__ __launch_bounds__(256) void k_gemm(const u16* __restrict__ A, const u16* __restrict__ Wt,
                                              const float* __restrict__ bias, void* __restrict__ Cout,
                                              const int N, const int K, const int ldc,
                                              const int* __restrict__ flagp) {
  constexpr int RT = TM / 16;
  constexpr int CPW = TN / 64;
  const int bm = blockIdx.x, bn = blockIdx.y;
  const int tid = threadIdx.x, wv = tid >> 6, lane = tid & 63;
  __shared__ __align__(16) u16 As[TM][72];
  float4_ acc[CPW][RT];
#pragma unroll
  for (int ci = 0; ci < CPW; ++ci)
#pragma unroll
    for (int rt = 0; rt < RT; ++rt) acc[ci][rt] = splat4(0.f);
  const int nk = K >> 6;
  for (int kc = 0; kc < nk; ++kc) {
    __syncthreads();
    for (int idx = tid; idx < TM * 4; idx += 256) {
      const int r = idx >> 2, sg = idx & 3;
      const u16* src = A + (long long)(bm * TM + r) * K + kc * 64 + sg * 16;
      *(short8a*)&As[r][sg * 16] = *(const short8a*)src;
      *(short8a*)&As[r][sg * 16 + 8] = *(const short8a*)(src + 8);
    }
    __syncthreads();
#pragma unroll
    for (int kk = 0; kk < 2; ++kk) {
      short8 af[RT];
#pragma unroll
      for (int rt = 0; rt < RT; ++rt)
        af[rt] = *(const short8a*)&As[rt * 16 + (lane & 15)][kk * 32 + (lane >> 4) * 8];
#pragma unroll
      for (int ci = 0; ci < CPW; ++ci) {
        const int ct = wv + ci * 4;
        const short8 bf = *(const short8a*)(Wt + (long long)(bn * TN + ct * 16 + (lane & 15)) * K +
                                            kc * 64 + kk * 32 + (lane >> 4) * 8);
#pragma unroll
        for (int rt = 0; rt < RT; ++rt) acc[ci][rt] = MFMA16(af[rt], bf, acc[ci][rt]);
      }
    }
  }
  const int isbf = (OUTM == 1) ? *flagp : 0;
#pragma unroll
  for (int ci = 0; ci < CPW; ++ci)
#pragma unroll
    for (int rt = 0; rt < RT; ++rt)
#pragma unroll
      for (int r = 0; r < 4; ++r) {
        const int row = bm * TM + rt * 16 + (lane >> 4) * 4 + r;
        const int col = bn * TN + (wv + ci * 4) * 16 + (lane & 15);
        if (col < N) {
          const float v = acc[ci][rt][r] + bias[col];
          long long orow;
          if (PERM == 0) orow = row;
          else if (PERM == 1) orow = (long long)(row & 255) * 64 + (row >> 8);
          else orow = (long long)(row & 63) * 256 + (row >> 6);
          if (OUTM == 0) ((u16*)Cout)[orow * ldc + col] = f2b(v);
          else if (isbf) ((u16*)Cout)[orow * ldc + col] = f2b(v);
          else ((float*)Cout)[orow * ldc + col] = v;
        }
      }
}

// ---------------- persistent LSTM scan (one layer, both dirs) ----------------
// grid (16, 2=dir). Block owns 32 hidden units; whh slice (128 rows x 512) in
// LDS (XOR-swizzled). Per step: gates = pre[t] + h_prev @ whh_slice^T, update
// c (regs) / h, publish h to global double buffer, flag barrier over 16 blocks.
__global__ __launch_bounds__(256) void k_scan(const u16* __restrict__ pre0, const u16* __restrict__ pre1,
                                              const u16* __restrict__ whh0, const u16* __restrict__ whh1,
                                              u16* __restrict__ o_out, u16* __restrict__ hbuf,
                                              int* __restrict__ cnt) {
  const int dir = blockIdx.y, blk = blockIdx.x;
  const u16* pre = dir ? pre1 : pre0;
  const u16* whh = dir ? whh1 : whh0;
  u16* hb = hbuf + dir * (2 * 64 * 512);
  int* mycnt = cnt + dir * 256;
  const int u0 = blk * 32;
  __shared__ __align__(16) u16 wsw[128 * 512];  // 128KB, byte-indexed w/ XOR swizzle
  const int tid = threadIdx.x, wv = tid >> 6, lane = tid & 63;
  for (int idx = tid; idx < 128 * 4; idx += 256) {
    const int lr = idx >> 2, q = idx & 3;
    const int g = lr >> 5, uu = lr & 31;
    const u16* src = whh + (long long)(g * 512 + u0 + uu) * 512 + q * 128;
#pragma unroll
    for (int i = 0; i < 16; ++i) {
      const int ke = q * 128 + i * 8;
      const int boff = lr * 1024 + ((ke * 2) ^ ((lr & 7) << 4));
      *(short8a*)((char*)wsw + boff) = *(const short8a*)(src + i * 8);
    }
  }
  float c[2][4];
#pragma unroll
  for (int ut = 0; ut < 2; ++ut)
#pragma unroll
    for (int r = 0; r < 4; ++r) c[ut][r] = 0.f;
  __syncthreads();

  for (int tt = 0; tt < 256; ++tt) {
    const int t = dir ? (255 - tt) : tt;
    const u16* hrd = hb + (tt & 1) * (64 * 512);
    u16* hwr = hb + ((tt + 1) & 1) * (64 * 512);
    // preload h_prev fragments (issued early, hidden under MFMA)
    short8 a[16];
#pragma unroll
    for (int kc = 0; kc < 16; ++kc)
      a[kc] = *(const short8a*)(hrd + (wv * 16 + (lane & 15)) * 512 + kc * 32 + (lane >> 4) * 8);
    // preload pre-gate values (consumed at activation)
    u16 pu[2][4][4];
#pragma unroll
    for (int ut = 0; ut < 2; ++ut)
#pragma unroll
      for (int g = 0; g < 4; ++g)
#pragma unroll
        for (int r = 0; r < 4; ++r) {
          const int b = wv * 16 + (lane >> 4) * 4 + r;
          pu[ut][g][r] = pre[(long long)(t * 64 + b) * 2048 + g * 512 + u0 + ut * 16 + (lane & 15)];
        }
    float4_ acc[2][4];
#pragma unroll
    for (int ut = 0; ut < 2; ++ut)
#pragma unroll
      for (int g = 0; g < 4; ++g) acc[ut][g] = splat4(0.f);
#pragma unroll
    for (int kc = 0; kc < 16; ++kc) {
#pragma unroll
      for (int ut = 0; ut < 2; ++ut)
#pragma unroll
        for (int g = 0; g < 4; ++g) {
          const int lr = g * 32 + ut * 16 + (lane & 15);
          const int boff = lr * 1024 + (((kc * 32 + (lane >> 4) * 8) * 2) ^ ((lr & 7) << 4));
          const short8 bfr = *(const short8a*)((const char*)wsw + boff);
          acc[ut][g] = MFMA16(a[kc], bfr, acc[ut][g]);
        }
    }
#pragma unroll
    for (int ut = 0; ut < 2; ++ut)
#pragma unroll
      for (int r = 0; r < 4; ++r) {
        const float iv = acc[ut][0][r] + b2f(pu[ut][0][r]);
        const float fv = acc[ut][1][r] + b2f(pu[ut][1][r]);
        const float gv = acc[ut][2][r] + b2f(pu[ut][2][r]);
        const float ov = acc[ut][3][r] + b2f(pu[ut][3][r]);
        float& cc = c[ut][r];
        cc = sigm(fv) * cc + sigm(iv) * tanh_(gv);
        const float h = sigm(ov) * tanh_(cc);
        const int b = wv * 16 + (lane >> 4) * 4 + r;
        const int u = u0 + ut * 16 + (lane & 15);
        const u16 hv = f2b(h);
        hwr[b * 512 + u] = hv;
        o_out[(long long)(t * 64 + b) * 1024 + dir * 512 + u] = hv;
      }
    // inter-block barrier (16 blocks per dir)
    __threadfence();
    __syncthreads();
    if (tid == 0) {
      __hip_atomic_fetch_add(&mycnt[tt], 1, __ATOMIC_ACQ_REL, __HIP_MEMORY_SCOPE_AGENT);
      while (__hip_atomic_load(&mycnt[tt], __ATOMIC_ACQUIRE, __HIP_MEMORY_SCOPE_AGENT) < 16) {
        __builtin_amdgcn_s_sleep(2);
      }
    }
    __syncthreads();
  }
}

// ---------------- launcher ----------------
static constexpr long long OFF_WT = 0;                  // u16 x 9,830,400 (weights bf16 + tag pad)
static constexpr long long OFF_BIAS = 19660800;         // f32 x 9,536 (summed biases + pads)
static constexpr long long OFF_CAT = 19698944;          // u16 16384x512
static constexpr long long OFF_EMB = 36476160;          // u16 16384x256
static constexpr long long OFF_PRE = 44864768;          // u16 2 x 16384x2048
static constexpr long long OFF_O1 = 179082496;          // u16 16384x1024
static constexpr long long OFF_O2 = 212636928;          // u16 16384x1024
static constexpr long long OFF_SYNC = 246191360;        // cnts (4KB) + h double-buffers (512KB)
static constexpr long long SYNC_BYTES = 4096 + 524288;
static constexpr long long OFF_FLAG = OFF_SYNC + SYNC_BYTES;

extern "C" void kernel_launch(void* const* d_in, const int* in_sizes, int n_in,
                              void* d_out, int out_size, void* d_ws, size_t ws_size,
                              hipStream_t stream) {
  char* ws = (char*)d_ws;
  u16* wt = (u16*)(ws + OFF_WT);
  float* biasp = (float*)(ws + OFF_BIAS);
  u16* cat = (u16*)(ws + OFF_CAT);
  u16* emb = (u16*)(ws + OFF_EMB);
  u16* pre0 = (u16*)(ws + OFF_PRE);
  u16* pre1 = pre0 + (long long)16384 * 2048;
  u16* o1 = (u16*)(ws + OFF_O1);
  u16* o2 = (u16*)(ws + OFF_O2);
  int* cnt1 = (int*)(ws + OFF_SYNC);
  int* cnt2 = cnt1 + 512;
  u16* h1 = (u16*)(ws + OFF_SYNC + 4096);
  u16* h2 = h1 + 131072;
  int* flag = (int*)(ws + OFF_FLAG);

  hipMemsetAsync(ws + OFF_SYNC, 0, SYNC_BYTES, stream);
  k_detect<<<1, 256, 0, stream>>>((const unsigned*)d_in[30], flag);

  WSegs wsg;
  const int widx[14] = {4, 5, 8, 9, 12, 13, 16, 17, 20, 21, 24, 25, 28, 30};
  const int wdst[15] = {0, 32768, 98304, 131072, 196608, 720896, 1769472, 2293760,
                        3342336, 5439488, 6488064, 8585216, 9633792, 9764864, 9816064};
  const int wn[15] = {32768, 65536, 32768, 65536, 524288, 1048576, 524288, 1048576,
                      2097152, 1048576, 2097152, 1048576, 131072, 51200, 14336};
  for (int j = 0; j < 14; ++j) { wsg.src[j] = d_in[widx[j]]; wsg.dst[j] = wdst[j]; wsg.n[j] = wn[j]; }
  wsg.src[14] = nullptr; wsg.dst[14] = wdst[14]; wsg.n[14] = wn[14];
  k_convw<<<1024, 256, 0, stream>>>(wsg, wt, flag);

  BSegs bsg;
  const int ba[8] = {6, 10, 14, 18, 22, 26, 29, 31};
  const int bb[8] = {7, 11, 15, 19, 23, 27, -1, -1};
  const int bdst[8] = {0, 512, 1024, 3072, 5120, 7168, 9216, 9472};
  const int bn_[8] = {512, 512, 2048, 2048, 2048, 2048, 256, 50};
  const int bnp[8] = {512, 512, 2048, 2048, 2048, 2048, 256, 64};
  for (int j = 0; j < 8; ++j) {
    bsg.a[j] = d_in[ba[j]];
    bsg.b[j] = (bb[j] >= 0) ? d_in[bb[j]] : nullptr;
    bsg.dst[j] = bdst[j]; bsg.n[j] = bn_[j]; bsg.np[j] = bnp[j];
  }
  k_convb<<<40, 256, 0, stream>>>(bsg, biasp, flag);

  k_wordgather<<<16384, 128, 0, stream>>>((const int*)d_in[0], d_in[2], cat, flag);
  k_char<<<dim3(256, 2), 256, 0, stream>>>((const int*)d_in[1], d_in[3],
                                           wt + 0, wt + 32768, wt + 98304, wt + 131072,
                                           biasp + 0, biasp + 512, cat, flag);
  // embeds[s*64+b] = cat[n] @ w_final^T + b_final
  k_gemm<64, 64, 1, 0><<<dim3(256, 4), 256, 0, stream>>>(cat, wt + 9633792, biasp + 9216, emb, 256, 512, 256, flag);
  // layer-1 input gates
  k_gemm<128, 256, 0, 0><<<dim3(128, 8), 256, 0, stream>>>(emb, wt + 196608, biasp + 1024, pre0, 2048, 256, 2048, flag);
  k_gemm<128, 256, 0, 0><<<dim3(128, 8), 256, 0, stream>>>(emb, wt + 1769472, biasp + 3072, pre1, 2048, 256, 2048, flag);
  k_scan<<<dim3(16, 2), 256, 0, stream>>>(pre0, pre1, wt + 720896, wt + 2293760, o1, h1, cnt1);
  // layer-2 input gates (reuse pre buffers)
  k_gemm<128, 256, 0, 0><<<dim3(128, 8), 256, 0, stream>>>(o1, wt + 3342336, biasp + 5120, pre0, 2048, 1024, 2048, flag);
  k_gemm<128, 256, 0, 0><<<dim3(128, 8), 256, 0, stream>>>(o1, wt + 6488064, biasp + 7168, pre1, 2048, 1024, 2048, flag);
  k_scan<<<dim3(16, 2), 256, 0, stream>>>(pre0, pre1, wt + 5439488, wt + 8585216, o2, h2, cnt2);
  // tag projection, perm to [B,S,50]
  k_gemm<64, 64, 2, 1><<<dim3(256, 1), 256, 0, stream>>>(o2, wt + 9764864, biasp + 9472, d_out, 50, 1024, 50, flag);
}

// Round 2
// 5552.114 us; speedup vs baseline: 1.0972x; 1.0972x over previous
//
// BiLSTM tagger — MI355X. Round 2: k_scan sync overhaul.
// Change log vs R1: persistent scan now uses fine-grained device-scope h
// exchange (relaxed agent atomic u64 stores + single acquire fence) instead of
// __threadfence + acquire-spin (which did a full L2 writeback + an L2
// invalidate per poll -> 10us/step). MFMA operands swapped so C rows = hidden
// units -> h/o/pre accesses are contiguous u64 per thread.
#include <hip/hip_runtime.h>

typedef unsigned short u16;
typedef unsigned long long ull;
typedef short short8 __attribute__((ext_vector_type(8)));
typedef float float4_ __attribute__((ext_vector_type(4)));
typedef short8 short8a __attribute__((may_alias));
typedef ull ulla __attribute__((may_alias));

#define MFMA16(a, b, c) __builtin_amdgcn_mfma_f32_16x16x32_bf16((a), (b), (c), 0, 0, 0)

static __device__ __forceinline__ float b2f(u16 v) { return __uint_as_float(((unsigned)v) << 16); }
static __device__ __forceinline__ u16 f2b(float f) {
  unsigned x = __float_as_uint(f);
  return (u16)((x + 0x7fffu + ((x >> 16) & 1u)) >> 16);
}
static __device__ __forceinline__ float ldv(const void* p, long long i, int isbf) {
  return isbf ? b2f(((const u16*)p)[i]) : ((const float*)p)[i];
}
static __device__ __forceinline__ float sigm(float x) { return 1.f / (1.f + __expf(-x)); }
static __device__ __forceinline__ float tanh_(float x) { return 1.f - 2.f / (__expf(2.f * x) + 1.f); }
static __device__ __forceinline__ float4_ splat4(float v) { float4_ r; r[0]=v; r[1]=v; r[2]=v; r[3]=v; return r; }

// ---------------- dtype detection (f32 vs bf16 input buffers) ----------------
__global__ __launch_bounds__(256) void k_detect(const unsigned* __restrict__ wtag, int* __restrict__ flag) {
  __shared__ int cs;
  if (threadIdx.x == 0) cs = 0;
  __syncthreads();
  int hits = 0;
  for (int i = threadIdx.x; i < 1024; i += 256) {
    unsigned b = (wtag[i] >> 8) & 0x7fu;
    hits += (b >= 0x36u && b <= 0x3fu) ? 1 : 0;
  }
  atomicAdd(&cs, hits);
  __syncthreads();
  if (threadIdx.x == 0) *flag = (cs > 512) ? 1 : 0;
}

// ---------------- weight conversion to bf16 workspace ----------------
struct WSegs { const void* src[15]; int dst[15]; int n[15]; };
__global__ __launch_bounds__(256) void k_convw(WSegs s, u16* __restrict__ wt, const int* __restrict__ flagp) {
  const int isbf = *flagp;
  const long long total = 9830400;
  for (long long i = (long long)blockIdx.x * 256 + threadIdx.x; i < total; i += (long long)gridDim.x * 256) {
    int k = 0;
#pragma unroll
    for (int j = 1; j < 15; ++j) if (i >= (long long)s.dst[j]) k = j;
    const long long loc = i - s.dst[k];
    float v = 0.f;
    if (s.src[k]) v = ldv(s.src[k], loc, isbf);
    wt[i] = f2b(v);
  }
}

struct BSegs { const void* a[8]; const void* b[8]; int dst[8]; int n[8]; int np[8]; };
__global__ __launch_bounds__(256) void k_convb(BSegs s, float* __restrict__ bias, const int* __restrict__ flagp) {
  const int isbf = *flagp;
  for (int i = blockIdx.x * 256 + threadIdx.x; i < 9536; i += gridDim.x * 256) {
    int k = 0;
#pragma unroll
    for (int j = 1; j < 8; ++j) if (i >= s.dst[j]) k = j;
    const int loc = i - s.dst[k];
    float v = 0.f;
    if (loc < s.n[k]) {
      v = ldv(s.a[k], loc, isbf);
      if (s.b[k]) v += ldv(s.b[k], loc, isbf);
    }
    bias[i] = v;
  }
}

// ---------------- word embedding gather into cat[:,0:256] ----------------
__global__ __launch_bounds__(128) void k_wordgather(const int* __restrict__ sent, const void* __restrict__ wemb,
                                                    u16* __restrict__ cat, const int* __restrict__ flagp) {
  const int n = blockIdx.x;
  const int idx = sent[n];
  const int isbf = *flagp;
  for (int d = threadIdx.x; d < 256; d += 128)
    cat[(long long)n * 512 + d] = f2b(ldv(wemb, (long long)idx * 256 + d, isbf));
}

// ---------------- char biLSTM: 64 seqs/block, 16 steps, D=64 H=128 ----------------
__global__ __launch_bounds__(256) void k_char(const int* __restrict__ cs, const void* __restrict__ wchar,
                                              const u16* __restrict__ wihF, const u16* __restrict__ whhF,
                                              const u16* __restrict__ wihB, const u16* __restrict__ whhB,
                                              const float* __restrict__ biasF, const float* __restrict__ biasB,
                                              u16* __restrict__ cat, const int* __restrict__ flagp) {
  const int dir = blockIdx.y;
  const int nb = blockIdx.x;
  const u16* wih = dir ? wihB : wihF;
  const u16* whh = dir ? whhB : whhF;
  const float* bias = dir ? biasB : biasF;
  const int isbf = *flagp;
  __shared__ __align__(16) u16 xs[64][72];
  __shared__ __align__(16) u16 hs[64][136];
  const int tid = threadIdx.x, wv = tid >> 6, lane = tid & 63;
  for (int i = tid; i < 64 * 136; i += 256) ((u16*)hs)[i] = 0;
  float c[2][4][4];
#pragma unroll
  for (int a1 = 0; a1 < 2; ++a1)
#pragma unroll
    for (int a2 = 0; a2 < 4; ++a2)
#pragma unroll
      for (int a3 = 0; a3 < 4; ++a3) c[a1][a2][a3] = 0.f;

  for (int tt = 0; tt < 16; ++tt) {
    const int t = dir ? (15 - tt) : tt;
    {
      const int sid = tid >> 2, part = tid & 3;
      const int n = nb * 64 + sid;
      const int idx = cs[n * 16 + t];
#pragma unroll
      for (int q = 0; q < 16; ++q) {
        const int d2 = part * 16 + q;
        float v = 0.f;
        if (idx != 0) v = ldv(wchar, (long long)idx * 64 + d2, isbf);
        xs[sid][d2] = f2b(v);
      }
    }
    __syncthreads();
    float4_ acc[2][4][4];
#pragma unroll
    for (int ut = 0; ut < 2; ++ut)
#pragma unroll
      for (int g = 0; g < 4; ++g) {
        const float bv = bias[g * 128 + (wv + 4 * ut) * 16 + (lane & 15)];
#pragma unroll
        for (int rt = 0; rt < 4; ++rt) acc[ut][g][rt] = splat4(bv);
      }
#pragma unroll
    for (int kc = 0; kc < 6; ++kc) {
      short8 a[4];
      if (kc < 2) {
#pragma unroll
        for (int rt = 0; rt < 4; ++rt)
          a[rt] = *(const short8a*)&xs[rt * 16 + (lane & 15)][kc * 32 + (lane >> 4) * 8];
      } else {
#pragma unroll
        for (int rt = 0; rt < 4; ++rt)
          a[rt] = *(const short8a*)&hs[rt * 16 + (lane & 15)][(kc - 2) * 32 + (lane >> 4) * 8];
      }
#pragma unroll
      for (int ut = 0; ut < 2; ++ut)
#pragma unroll
        for (int g = 0; g < 4; ++g) {
          const int col = g * 128 + (wv + 4 * ut) * 16 + (lane & 15);
          short8 bfr;
          if (kc < 2) bfr = *(const short8a*)(wih + col * 64 + kc * 32 + (lane >> 4) * 8);
          else        bfr = *(const short8a*)(whh + col * 128 + (kc - 2) * 32 + (lane >> 4) * 8);
#pragma unroll
          for (int rt = 0; rt < 4; ++rt) acc[ut][g][rt] = MFMA16(a[rt], bfr, acc[ut][g][rt]);
        }
    }
    __syncthreads();
#pragma unroll
    for (int ut = 0; ut < 2; ++ut)
#pragma unroll
      for (int rt = 0; rt < 4; ++rt)
#pragma unroll
        for (int r = 0; r < 4; ++r) {
          const float iv = acc[ut][0][rt][r];
          const float fv = acc[ut][1][rt][r];
          const float gv = acc[ut][2][rt][r];
          const float ov = acc[ut][3][rt][r];
          float& cc = c[ut][rt][r];
          cc = sigm(fv) * cc + sigm(iv) * tanh_(gv);
          const float h = sigm(ov) * tanh_(cc);
          const int seq = rt * 16 + (lane >> 4) * 4 + r;
          const int u = (wv + 4 * ut) * 16 + (lane & 15);
          const u16 hv = f2b(h);
          hs[seq][u] = hv;
          if (tt == 15) cat[(long long)(nb * 64 + seq) * 512 + 256 + dir * 128 + u] = hv;
        }
  }
}

// ---------------- generic MFMA GEMM ----------------
template <int TM, int TN, int PERM, int OUTM>
__global__ __launch_bounds__(256) void k_gemm(const u16* __restrict__ A, const u16* __restrict__ Wt,
                                              const float* __restrict__ bias, void* __restrict__ Cout,
                                              const int N, const int K, const int ldc,
                                              const int* __restrict__ flagp) {
  constexpr int RT = TM / 16;
  constexpr int CPW = TN / 64;
  const int bm = blockIdx.x, bn = blockIdx.y;
  const int tid = threadIdx.x, wv = tid >> 6, lane = tid & 63;
  __shared__ __align__(16) u16 As[TM][72];
  float4_ acc[CPW][RT];
#pragma unroll
  for (int ci = 0; ci < CPW; ++ci)
#pragma unroll
    for (int rt = 0; rt < RT; ++rt) acc[ci][rt] = splat4(0.f);
  const int nk = K >> 6;
  for (int kc = 0; kc < nk; ++kc) {
    __syncthreads();
    for (int idx = tid; idx < TM * 4; idx += 256) {
      const int r = idx >> 2, sg = idx & 3;
      const u16* src = A + (long long)(bm * TM + r) * K + kc * 64 + sg * 16;
      *(short8a*)&As[r][sg * 16] = *(const short8a*)src;
      *(short8a*)&As[r][sg * 16 + 8] = *(const short8a*)(src + 8);
    }
    __syncthreads();
#pragma unroll
    for (int kk = 0; kk < 2; ++kk) {
      short8 af[RT];
#pragma unroll
      for (int rt = 0; rt < RT; ++rt)
        af[rt] = *(const short8a*)&As[rt * 16 + (lane & 15)][kk * 32 + (lane >> 4) * 8];
#pragma unroll
      for (int ci = 0; ci < CPW; ++ci) {
        const int ct = wv + ci * 4;
        const short8 bf = *(const short8a*)(Wt + (long long)(bn * TN + ct * 16 + (lane & 15)) * K +
                                            kc * 64 + kk * 32 + (lane >> 4) * 8);
#pragma unroll
        for (int rt = 0; rt < RT; ++rt) acc[ci][rt] = MFMA16(af[rt], bf, acc[ci][rt]);
      }
    }
  }
  const int isbf = (OUTM == 1) ? *flagp : 0;
#pragma unroll
  for (int ci = 0; ci < CPW; ++ci)
#pragma unroll
    for (int rt = 0; rt < RT; ++rt)
#pragma unroll
      for (int r = 0; r < 4; ++r) {
        const int row = bm * TM + rt * 16 + (lane >> 4) * 4 + r;
        const int col = bn * TN + (wv + ci * 4) * 16 + (lane & 15);
        if (col < N) {
          const float v = acc[ci][rt][r] + bias[col];
          long long orow;
          if (PERM == 0) orow = row;
          else if (PERM == 1) orow = (long long)(row & 255) * 64 + (row >> 8);
          else orow = (long long)(row & 63) * 256 + (row >> 6);
          if (OUTM == 0) ((u16*)Cout)[orow * ldc + col] = f2b(v);
          else if (isbf) ((u16*)Cout)[orow * ldc + col] = f2b(v);
          else ((float*)Cout)[orow * ldc + col] = v;
        }
      }
}

// ---------------- persistent LSTM scan (one layer, both dirs) ----------------
// grid (16, 2=dir). Block owns 32 hidden units. Swapped MFMA: C row = unit,
// col = batch -> per-thread outputs contiguous u64. h exchange: relaxed agent
// atomic u64 stores (write-through) + vmcnt drain + relaxed counter add;
// readers spin relaxed, then ONE acquire fence, then plain b128 h loads.
__global__ __launch_bounds__(256) void k_scan(const u16* __restrict__ pre0, const u16* __restrict__ pre1,
                                              const u16* __restrict__ whh0, const u16* __restrict__ whh1,
                                              u16* __restrict__ o_out, u16* __restrict__ hbuf,
                                              int* __restrict__ cnt) {
  const int dir = blockIdx.y, blk = blockIdx.x;
  const u16* pre = dir ? pre1 : pre0;
  const u16* whh = dir ? whh1 : whh0;
  u16* hb = hbuf + dir * (2 * 64 * 512);
  int* mycnt = cnt + dir * 256;
  const int u0 = blk * 32;
  __shared__ __align__(16) u16 wsw[128 * 512];  // 128KB, byte-indexed w/ XOR swizzle
  const int tid = threadIdx.x, wv = tid >> 6, lane = tid & 63;
  for (int idx = tid; idx < 128 * 4; idx += 256) {
    const int lr = idx >> 2, q = idx & 3;
    const int g = lr >> 5, uu = lr & 31;
    const u16* src = whh + (long long)(g * 512 + u0 + uu) * 512 + q * 128;
#pragma unroll
    for (int i = 0; i < 16; ++i) {
      const int ke = q * 128 + i * 8;
      const int boff = lr * 1024 + ((ke * 2) ^ ((lr & 7) << 4));
      *(short8a*)((char*)wsw + boff) = *(const short8a*)(src + i * 8);
    }
  }
  const int b = wv * 16 + (lane & 15);   // batch this thread covers (C col)
  const int klo = (lane >> 4) * 8;       // k sub-offset within fragment
  const int usub = (lane >> 4) * 4;      // unit sub-offset within C tile row
  float c[2][4];
#pragma unroll
  for (int ut = 0; ut < 2; ++ut)
#pragma unroll
    for (int r = 0; r < 4; ++r) c[ut][r] = 0.f;
  __syncthreads();

  // preload pre-gates for step 0 (u64 per (ut,gate): 4 consecutive units)
  ull puc[8];
  {
    const int t0 = dir ? 255 : 0;
#pragma unroll
    for (int ut = 0; ut < 2; ++ut)
#pragma unroll
      for (int g = 0; g < 4; ++g)
        puc[ut * 4 + g] = *(const ulla*)(pre + (long long)(t0 * 64 + b) * 2048 + g * 512 + u0 + ut * 16 + usub);
  }

  for (int tt = 0; tt < 256; ++tt) {
    const int t = dir ? (255 - tt) : tt;
    const u16* hrd = hb + (tt & 1) * (64 * 512);
    u16* hwr = hb + ((tt + 1) & 1) * (64 * 512);
    // h fragments (operand1): row = batch b, k (units) contiguous
    short8 a[16];
#pragma unroll
    for (int kc = 0; kc < 16; ++kc)
      a[kc] = *(const short8a*)(hrd + b * 512 + kc * 32 + klo);
    // prefetch next step's pre-gates (completes under MFMA, consumed next iter)
    ull pun[8];
    {
      const int ttn = (tt < 255) ? tt + 1 : tt;
      const int tn = dir ? (255 - ttn) : ttn;
#pragma unroll
      for (int ut = 0; ut < 2; ++ut)
#pragma unroll
        for (int g = 0; g < 4; ++g)
          pun[ut * 4 + g] = *(const ulla*)(pre + (long long)(tn * 64 + b) * 2048 + g * 512 + u0 + ut * 16 + usub);
    }
    float4_ acc[2][4];
#pragma unroll
    for (int ut = 0; ut < 2; ++ut)
#pragma unroll
      for (int g = 0; g < 4; ++g) acc[ut][g] = splat4(0.f);
#pragma unroll
    for (int kc = 0; kc < 16; ++kc) {
#pragma unroll
      for (int ut = 0; ut < 2; ++ut)
#pragma unroll
        for (int g = 0; g < 4; ++g) {
          const int lr = g * 32 + ut * 16 + (lane & 15);
          const int boff = lr * 1024 + (((kc * 32 + klo) * 2) ^ ((lr & 7) << 4));
          const short8 bfr = *(const short8a*)((const char*)wsw + boff);
          acc[ut][g] = MFMA16(bfr, a[kc], acc[ut][g]);  // row=unit, col=batch
        }
    }
    ull hov[2];
#pragma unroll
    for (int ut = 0; ut < 2; ++ut) {
      ull hv = 0;
#pragma unroll
      for (int r = 0; r < 4; ++r) {
        const float iv = acc[ut][0][r] + b2f((u16)(puc[ut * 4 + 0] >> (16 * r)));
        const float fv = acc[ut][1][r] + b2f((u16)(puc[ut * 4 + 1] >> (16 * r)));
        const float gv = acc[ut][2][r] + b2f((u16)(puc[ut * 4 + 2] >> (16 * r)));
        const float ov = acc[ut][3][r] + b2f((u16)(puc[ut * 4 + 3] >> (16 * r)));
        float& cc = c[ut][r];
        cc = sigm(fv) * cc + sigm(iv) * tanh_(gv);
        const float h = sigm(ov) * tanh_(cc);
        hv |= (ull)f2b(h) << (16 * r);
      }
      hov[ut] = hv;
      // device-scope write-through publish of 4 contiguous h units
      __hip_atomic_store((ull*)(hwr + b * 512 + u0 + ut * 16 + usub), hv,
                         __ATOMIC_RELAXED, __HIP_MEMORY_SCOPE_AGENT);
    }
    asm volatile("s_waitcnt vmcnt(0)" ::: "memory");  // h stores at coherent point
    __syncthreads();                                   // all waves drained
    if (tid == 0)
      __hip_atomic_fetch_add(&mycnt[tt], 1, __ATOMIC_RELAXED, __HIP_MEMORY_SCOPE_AGENT);
    // o_out writes + pu rotate overlap the spin
#pragma unroll
    for (int ut = 0; ut < 2; ++ut)
      *(ulla*)(o_out + (long long)(t * 64 + b) * 1024 + dir * 512 + u0 + ut * 16 + usub) = hov[ut];
#pragma unroll
    for (int i = 0; i < 8; ++i) puc[i] = pun[i];
    if (tt != 255) {
      if (tid == 0) {
        while (__hip_atomic_load(&mycnt[tt], __ATOMIC_RELAXED, __HIP_MEMORY_SCOPE_AGENT) < 16)
          __builtin_amdgcn_s_sleep(1);
      }
      __syncthreads();
      __builtin_amdgcn_fence(__ATOMIC_ACQUIRE, "agent");  // one inv; h loads fetch fresh
    }
  }
}

// ---------------- launcher ----------------
static constexpr long long OFF_WT = 0;
static constexpr long long OFF_BIAS = 19660800;
static constexpr long long OFF_CAT = 19698944;
static constexpr long long OFF_EMB = 36476160;
static constexpr long long OFF_PRE = 44864768;
static constexpr long long OFF_O1 = 179082496;
static constexpr long long OFF_O2 = 212636928;
static constexpr long long OFF_SYNC = 246191360;
static constexpr long long SYNC_BYTES = 4096 + 524288;
static constexpr long long OFF_FLAG = OFF_SYNC + SYNC_BYTES;

extern "C" void kernel_launch(void* const* d_in, const int* in_sizes, int n_in,
                              void* d_out, int out_size, void* d_ws, size_t ws_size,
                              hipStream_t stream) {
  char* ws = (char*)d_ws;
  u16* wt = (u16*)(ws + OFF_WT);
  float* biasp = (float*)(ws + OFF_BIAS);
  u16* cat = (u16*)(ws + OFF_CAT);
  u16* emb = (u16*)(ws + OFF_EMB);
  u16* pre0 = (u16*)(ws + OFF_PRE);
  u16* pre1 = pre0 + (long long)16384 * 2048;
  u16* o1 = (u16*)(ws + OFF_O1);
  u16* o2 = (u16*)(ws + OFF_O2);
  int* cnt1 = (int*)(ws + OFF_SYNC);
  int* cnt2 = cnt1 + 512;
  u16* h1 = (u16*)(ws + OFF_SYNC + 4096);
  u16* h2 = h1 + 131072;
  int* flag = (int*)(ws + OFF_FLAG);

  hipMemsetAsync(ws + OFF_SYNC, 0, SYNC_BYTES, stream);
  k_detect<<<1, 256, 0, stream>>>((const unsigned*)d_in[30], flag);

  WSegs wsg;
  const int widx[14] = {4, 5, 8, 9, 12, 13, 16, 17, 20, 21, 24, 25, 28, 30};
  const int wdst[15] = {0, 32768, 98304, 131072, 196608, 720896, 1769472, 2293760,
                        3342336, 5439488, 6488064, 8585216, 9633792, 9764864, 9816064};
  const int wn[15] = {32768, 65536, 32768, 65536, 524288, 1048576, 524288, 1048576,
                      2097152, 1048576, 2097152, 1048576, 131072, 51200, 14336};
  for (int j = 0; j < 14; ++j) { wsg.src[j] = d_in[widx[j]]; wsg.dst[j] = wdst[j]; wsg.n[j] = wn[j]; }
  wsg.src[14] = nullptr; wsg.dst[14] = wdst[14]; wsg.n[14] = wn[14];
  k_convw<<<1024, 256, 0, stream>>>(wsg, wt, flag);

  BSegs bsg;
  const int ba[8] = {6, 10, 14, 18, 22, 26, 29, 31};
  const int bb[8] = {7, 11, 15, 19, 23, 27, -1, -1};
  const int bdst[8] = {0, 512, 1024, 3072, 5120, 7168, 9216, 9472};
  const int bn_[8] = {512, 512, 2048, 2048, 2048, 2048, 256, 50};
  const int bnp[8] = {512, 512, 2048, 2048, 2048, 2048, 256, 64};
  for (int j = 0; j < 8; ++j) {
    bsg.a[j] = d_in[ba[j]];
    bsg.b[j] = (bb[j] >= 0) ? d_in[bb[j]] : nullptr;
    bsg.dst[j] = bdst[j]; bsg.n[j] = bn_[j]; bsg.np[j] = bnp[j];
  }
  k_convb<<<40, 256, 0, stream>>>(bsg, biasp, flag);

  k_wordgather<<<16384, 128, 0, stream>>>((const int*)d_in[0], d_in[2], cat, flag);
  k_char<<<dim3(256, 2), 256, 0, stream>>>((const int*)d_in[1], d_in[3],
                                           wt + 0, wt + 32768, wt + 98304, wt + 131072,
                                           biasp + 0, biasp + 512, cat, flag);
  k_gemm<64, 64, 1, 0><<<dim3(256, 4), 256, 0, stream>>>(cat, wt + 9633792, biasp + 9216, emb, 256, 512, 256, flag);
  k_gemm<128, 256, 0, 0><<<dim3(128, 8), 256, 0, stream>>>(emb, wt + 196608, biasp + 1024, pre0, 2048, 256, 2048, flag);
  k_gemm<128, 256, 0, 0><<<dim3(128, 8), 256, 0, stream>>>(emb, wt + 1769472, biasp + 3072, pre1, 2048, 256, 2048, flag);
  k_scan<<<dim3(16, 2), 256, 0, stream>>>(pre0, pre1, wt + 720896, wt + 2293760, o1, h1, cnt1);
  k_gemm<128, 256, 0, 0><<<dim3(128, 8), 256, 0, stream>>>(o1, wt + 3342336, biasp + 5120, pre0, 2048, 1024, 2048, flag);
  k_gemm<128, 256, 0, 0><<<dim3(128, 8), 256, 0, stream>>>(o1, wt + 6488064, biasp + 7168, pre1, 2048, 1024, 2048, flag);
  k_scan<<<dim3(16, 2), 256, 0, stream>>>(pre0, pre1, wt + 5439488, wt + 8585216, o2, h2, cnt2);
  k_gemm<64, 64, 2, 1><<<dim3(256, 1), 256, 0, stream>>>(o2, wt + 9764864, biasp + 9472, d_out, 50, 1024, 50, flag);
}